// Round 7
// baseline (127.438 us; speedup 1.0000x reference)
//
#include <hip/hip_runtime.h>

// Pink-noise 6-pole IIR — warmup-tile parallel, ONE kernel, zero inter-block deps.
//
// Key fact: the slowest pole is 0.99886, so A^8192 = 8.7e-5 — the filter
// forgets its history in a few thousand samples. Each block computes one
// 8192-sample output tile preceded by an 8192-sample warmup scanned from zero
// state. Truncation error <= ~1e-5 (tolerance 7.8e-3); tile 0 of each channel
// is EXACT (zero prefix = true zero init).
//
// Round-6 lesson: 64 KB LDS -> 2 blocks/CU -> phase-serialized (hbm 38%,
// VALU 39%, both half-idle). Fix: the warmup half never needs LDS — warmup
// threads consume contiguous 32-sample chunks, so they read global directly
// (128 B/thread, L2/L3-served: r6 showed warmup re-reads never hit HBM).
// LDS now holds only the output tile (32 KB) -> 3 blocks/CU resident.
//
// __launch_bounds__ 2nd arg acts as min BLOCKS/CU on this toolchain
// (r4: (512,2)->cap 128, r5: (512,4)->cap 64 + 580 MB spills, r3: (1024,4)
// crashed). (512,3) -> cap ~84 >= the ~52-reg live set: no spills, 24 waves/CU.

constexpr int kL = 65536;               // samples per channel
constexpr int kThr = 512;               // threads per block = 8 waves
constexpr int kWaves = kThr / 64;       // 8
constexpr int kHalf = kThr / 2;         // 256 threads per half
constexpr int kT = 8192;                // output tile per block (LDS-staged)
constexpr int kW = 8192;                // warmup samples (global-direct)
constexpr int kPT = 32;                 // samples per thread (both halves)
constexpr int kTilesPerCh = kL / kT;    // 8

// XOR swizzle: bank-balances both the 32-strided chunk reads and the linear
// float4 access patterns; involution; keeps float4 groups (bits 0-1) intact.
__device__ __forceinline__ int swz(int i) {
    return i ^ (((i >> 5) & 7) << 2);
}

__global__ __launch_bounds__(kThr, 3) void pink_tile(
    const float* __restrict__ white, float* __restrict__ pink)
{
    constexpr float A[6] = {0.99886f, 0.99332f, 0.969f, 0.8665f, 0.55f, -0.7616f};
    constexpr float C[6] = {0.0555179f, 0.0750759f, 0.153852f, 0.3104856f, 0.5329522f, -0.016898f};
    constexpr float B6G = 0.115926f, DIRECT = 0.5362f, OUTG = 0.11f;

    __shared__ __align__(16) float buf[kT];      // 32 KiB: output tile only
    __shared__ float swv[6][kWaves];

    const int tid = threadIdx.x, lane = tid & 63, wave = tid >> 6;
    const int ch = blockIdx.x / kTilesPerCh;
    const int tI = blockIdx.x % kTilesPerCh;
    const size_t outBase = (size_t)ch * kL + (size_t)tI * kT;

    // Constants: mPT = A^32, pmL = (A^32)^lane, Mwv = (A^32)^64 = A^2048.
    // (Underflow to 0 for fast poles is numerically correct.)
    float mPT[6], pmL[6], Mwv[6];
    #pragma unroll
    for (int p = 0; p < 6; ++p) {
        float q = A[p];
        #pragma unroll
        for (int i = 0; i < 5; ++i) q *= q;          // A^32
        mPT[p] = q;
        float pm = 1.f, qq = q;
        #pragma unroll
        for (int b = 0; b < 6; ++b) { if ((lane >> b) & 1) pm *= qq; qq *= qq; }
        pmL[p] = pm;
        Mwv[p] = qq;                                  // (A^32)^64 = A^2048
    }

    float e[6] = {0.f, 0.f, 0.f, 0.f, 0.f, 0.f};

    if (tid < kHalf) {
        // ---- Warmup half: contiguous 32-sample chunk straight from global.
        // Wave w (0..3) covers warmup samples [2048w, 2048w+2048).
        // tI==0: warmup input is zeros (exact zero init) — no loads at all.
        if (tI != 0) {
            const float* g = white + outBase - kW + (size_t)kPT * tid;
            #pragma unroll
            for (int kk = 0; kk < kPT / 4; ++kk) {
                const float4 x = *(const float4*)(g + 4 * kk);
                const float* xp = &x.x;
                #pragma unroll
                for (int j = 0; j < 4; ++j) {
                    const float ww = xp[j];
                    #pragma unroll
                    for (int p = 0; p < 6; ++p) e[p] = fmaf(A[p], e[p], ww * C[p]);
                }
            }
        }
    } else {
        // ---- Output half: coalesced load -> swizzled LDS (2 groups of 4
        // float4 to keep the register peak under the 84 cap).
        const int u = tid - kHalf;
        const float4* src4 = (const float4*)(white + outBase);
        #pragma unroll
        for (int g2 = 0; g2 < 2; ++g2) {
            float4 v[4];
            #pragma unroll
            for (int k = 0; k < 4; ++k) v[k] = src4[u + (g2 * 4 + k) * kHalf];
            #pragma unroll
            for (int k = 0; k < 4; ++k)
                *(float4*)&buf[swz(4 * (u + (g2 * 4 + k) * kHalf))] = v[k];
        }
    }
    __syncthreads();                 // LDS staged (warmup threads rendezvous)

    float pwl = 0.f;
    if (tid >= kHalf) {
        const int u = tid - kHalf;
        // Chunk scan from LDS (zero init).
        #pragma unroll
        for (int kk = 0; kk < kPT / 4; ++kk) {
            const float4 x = *(const float4*)&buf[swz(kPT * u + 4 * kk)];
            const float* xp = &x.x;
            #pragma unroll
            for (int j = 0; j < 4; ++j) {
                const float ww = xp[j];
                #pragma unroll
                for (int p = 0; p < 6; ++p) e[p] = fmaf(A[p], e[p], ww * C[p]);
            }
        }
        // Previous white sample for the b6 delay line (captured before the
        // recompute phase can overwrite the predecessor's slot).
        if (u == 0) pwl = (tI != 0) ? white[outBase - 1] : 0.f;
        else        pwl = buf[swz(kPT * u - 1)];
    }

    // Intra-wave affine scan (constant per-round multiplier) — all 8 waves.
    float mk[6];
    #pragma unroll
    for (int p = 0; p < 6; ++p) mk[p] = mPT[p];
    #pragma unroll
    for (int r = 0; r < 6; ++r) {
        const int off = 1 << r;
        float fe[6];
        #pragma unroll
        for (int p = 0; p < 6; ++p) fe[p] = __shfl_up(e[p], off);
        if (lane >= off) {
            #pragma unroll
            for (int p = 0; p < 6; ++p) e[p] = fmaf(mk[p], fe[p], e[p]);
        }
        #pragma unroll
        for (int p = 0; p < 6; ++p) mk[p] *= mk[p];
    }
    float ex[6];
    #pragma unroll
    for (int p = 0; p < 6; ++p) {
        ex[p] = __shfl_up(e[p], 1);
        if (lane == 0) ex[p] = 0.f;
    }
    if (lane == 63) {
        #pragma unroll
        for (int p = 0; p < 6; ++p) swv[p][wave] = e[p];
    }
    __syncthreads();                 // swv ready; all pass-1 buf reads done

    // Recompute + stage outputs (output half only). Incoming state: fold
    // zero-init through all previous waves (warmup waves 0-3 included),
    // then apply this lane's exclusive span.
    if (tid >= kHalf) {
        const int u = tid - kHalf;
        float b[6];
        #pragma unroll
        for (int p = 0; p < 6; ++p) {
            float X = 0.f;
            #pragma unroll
            for (int w2 = 0; w2 < kWaves; ++w2)
                if (w2 < wave) X = fmaf(Mwv[p], X, swv[p][w2]);
            b[p] = fmaf(pmL[p], X, ex[p]);
        }
        float b6 = B6G * pwl;
        #pragma unroll
        for (int kk = 0; kk < kPT / 4; ++kk) {
            const float4 x = *(const float4*)&buf[swz(kPT * u + 4 * kk)];
            const float* xp = &x.x;
            float4 o;
            float* op = &o.x;
            #pragma unroll
            for (int j = 0; j < 4; ++j) {
                const float ww = xp[j];
                #pragma unroll
                for (int p = 0; p < 6; ++p) b[p] = fmaf(A[p], b[p], ww * C[p]);
                const float sum = ((b[0]+b[1]) + (b[2]+b[3])) + ((b[4]+b[5]) + b6);
                op[j] = fmaf(DIRECT, ww, sum) * OUTG;
                b6 = B6G * ww;
            }
            *(float4*)&buf[swz(kPT * u + 4 * kk)] = o;
        }
    }
    __syncthreads();                 // outputs staged

    // Coalesced store: all 512 threads, 4 float4 each = 8192 floats.
    float4* dst4 = (float4*)(pink + outBase);
    #pragma unroll
    for (int k = 0; k < 4; ++k)
        dst4[tid + k * kThr] = *(const float4*)&buf[swz(4 * (tid + k * kThr))];
}

extern "C" void kernel_launch(void* const* d_in, const int* in_sizes, int n_in,
                              void* d_out, int out_size, void* d_ws, size_t ws_size,
                              hipStream_t stream) {
    const float* white = (const float*)d_in[0];
    float* pink = (float*)d_out;
    const int nCh = in_sizes[0] / kL;                 // 256 channels
    const int nBlk = nCh * kTilesPerCh;               // 2048 blocks

    hipLaunchKernelGGL(pink_tile, dim3(nBlk), dim3(kThr), 0, stream,
                       white, pink);
}